// Round 2
// baseline (133075.964 us; speedup 1.0000x reference)
//
#include <hip/hip_runtime.h>

#define T_LEN 4096
#define EMB   300
#define HD    256
#define G4    1024      // 4*HD (gate rows per direction)
#define N2    2048      // both directions
#define TAGS  12
#define NEGV  -10000.0f

// ---------------------------------------------------------------------------
// Kernel 1: g_in[t][dir*1024 + r] = embed[sent[t]] . W_ih_dir[r] + b_ih + b_hh
// Tiled f32 GEMM, M=4096 N=2048 K=300, 64x64 tiles, 256 thr, 4x4 per thread.
// ---------------------------------------------------------------------------
__global__ __launch_bounds__(256) void gin_gemm(
    const int* __restrict__ sent, const float* __restrict__ embed,
    const float* __restrict__ Wf, const float* __restrict__ Wb,
    const float* __restrict__ bihf, const float* __restrict__ bhhf,
    const float* __restrict__ bihb, const float* __restrict__ bhhb,
    float* __restrict__ gin)
{
    __shared__ float As[64][33];
    __shared__ float Bs[64][33];
    __shared__ int   sIdx[64];
    const int tid = threadIdx.x;
    const int bn = blockIdx.x;   // 0..31  (N tiles over 2048)
    const int bm = blockIdx.y;   // 0..63  (M tiles over 4096)
    if (tid < 64) sIdx[tid] = sent[bm*64 + tid];
    __syncthreads();

    float acc[4][4] = {};
    const int lr = tid >> 3;          // 0..31
    const int lk = (tid & 7) << 2;    // 0,4,..,28
    const int m0 = (tid >> 4) << 2;
    const int n0 = (tid & 15) << 2;

    for (int kc = 0; kc < 10; ++kc) {           // K chunks of 32 (covers 320, guard 300)
        const int k0 = kc*32 + lk;
        #pragma unroll
        for (int h = 0; h < 2; ++h) {
            const int row = lr + h*32;
            float4 va = make_float4(0.f,0.f,0.f,0.f);
            if (k0 + 3 < EMB)   // EMB % 4 == 0, so vectors are all-or-nothing
                va = *(const float4*)(embed + (long)sIdx[row]*EMB + k0);
            As[row][lk+0]=va.x; As[row][lk+1]=va.y; As[row][lk+2]=va.z; As[row][lk+3]=va.w;

            const int rn = bn*64 + row;          // tiles never straddle the 1024 boundary
            const float* bsrc = (rn < G4) ? (Wf + (long)rn*EMB) : (Wb + (long)(rn-G4)*EMB);
            float4 vb = make_float4(0.f,0.f,0.f,0.f);
            if (k0 + 3 < EMB)
                vb = *(const float4*)(bsrc + k0);
            Bs[row][lk+0]=vb.x; Bs[row][lk+1]=vb.y; Bs[row][lk+2]=vb.z; Bs[row][lk+3]=vb.w;
        }
        __syncthreads();
        #pragma unroll
        for (int kk = 0; kk < 32; ++kk) {
            float a[4], b[4];
            #pragma unroll
            for (int i = 0; i < 4; ++i) a[i] = As[m0+i][kk];
            #pragma unroll
            for (int i = 0; i < 4; ++i) b[i] = Bs[n0+i][kk];
            #pragma unroll
            for (int i = 0; i < 4; ++i)
                #pragma unroll
                for (int jj = 0; jj < 4; ++jj)
                    acc[i][jj] = fmaf(a[i], b[jj], acc[i][jj]);
        }
        __syncthreads();
    }

    #pragma unroll
    for (int i = 0; i < 4; ++i) {
        const int t = bm*64 + m0 + i;
        #pragma unroll
        for (int jj = 0; jj < 4; ++jj) {
            const int r = bn*64 + n0 + jj;
            const float bias = (r < G4) ? (bihf[r] + bhhf[r])
                                        : (bihb[r-G4] + bhhb[r-G4]);
            gin[(long)t*N2 + r] = acc[i][jj] + bias;
        }
    }
}

// ---------------------------------------------------------------------------
// Kernel 2: single-block-per-direction persistent BiLSTM recurrence.
// Block dir in {0,1}, 1024 threads = 16 waves on ONE CU. Thread r owns gate
// row r of W_hh (256 f32 pinned in VGPRs via asm anti-remat barrier). h lives
// in LDS; per-step sync is two __syncthreads() — no global handshake.
// ---------------------------------------------------------------------------
__global__ __launch_bounds__(1024, 1) void lstm_single(
    const float* __restrict__ Whhf, const float* __restrict__ Whhb,
    const float* __restrict__ h0, const float* __restrict__ c0,
    const float* __restrict__ gin, float* __restrict__ Hhist)
{
    const int dir = blockIdx.x;
    const int tid = threadIdx.x;

    const float4* wrow = (const float4*)((dir ? Whhb : Whhf) + (long)tid*HD);
    float4 w[64];
    #pragma unroll
    for (int k = 0; k < 64; ++k) {
        w[k] = wrow[k];
        // Opaque def: compiler can no longer rematerialize these as loads
        // inside the step loop -> true VGPR persistence (~256 regs of W).
        asm volatile("" : "+v"(w[k].x), "+v"(w[k].y), "+v"(w[k].z), "+v"(w[k].w));
    }

    __shared__ __align__(16) float hS[HD];
    __shared__ float gv[G4];

    float cst = 0.f;
    if (tid < HD) {
        cst = c0[dir*HD + tid];
        hS[tid] = h0[dir*HD + tid];
    }

    const float* ginD = gin + dir*G4;
    float gx = ginD[(long)(dir ? T_LEN-1 : 0)*N2 + tid];

    #pragma unroll 1
    for (int s = 0; s < T_LEN; ++s) {
        const int t = dir ? (T_LEN-1-s) : s;
        float gxn = 0.f;
        if (s+1 < T_LEN) {                        // prefetch next step's gin
            const int tn = dir ? (t-1) : (t+1);
            gxn = ginD[(long)tn*N2 + tid];
        }

        __syncthreads();                          // hS stable
        const float4* h4 = (const float4*)hS;     // uniform-address broadcast reads
        float a0=0.f, a1=0.f, a2=0.f, a3=0.f;
        #pragma unroll
        for (int k = 0; k < 64; ++k) {
            const float4 hv = h4[k];
            a0 = fmaf(w[k].x, hv.x, a0);
            a1 = fmaf(w[k].y, hv.y, a1);
            a2 = fmaf(w[k].z, hv.z, a2);
            a3 = fmaf(w[k].w, hv.w, a3);
        }
        gv[tid] = gx + ((a0+a1)+(a2+a3));
        __syncthreads();                          // gv ready; all hS reads done

        if (tid < HD) {                           // waves 0-3: pointwise update
            const float gi = gv[tid], gf = gv[HD+tid];
            const float gg = gv[2*HD+tid], go = gv[3*HD+tid];
            const float i_ = 1.f/(1.f + expf(-gi));
            const float f_ = 1.f/(1.f + expf(-gf));
            const float g_ = tanhf(gg);
            const float o_ = 1.f/(1.f + expf(-go));
            cst = fmaf(f_, cst, i_*g_);
            const float hv = o_ * tanhf(cst);
            hS[tid] = hv;                         // safe: nobody reads hS until next sync
            Hhist[(long)t*512 + dir*HD + tid] = hv;
        }
        gx = gxn;
    }
}

// ---------------------------------------------------------------------------
// Kernel 3: feats[t][tag] = [hf|hb][t] . W_tag[tag] + b_tag
// ---------------------------------------------------------------------------
__global__ __launch_bounds__(192) void feats_kernel(
    const float* __restrict__ Hhist, const float* __restrict__ Wtag,
    const float* __restrict__ btag, float* __restrict__ feats)
{
    __shared__ __align__(16) float Ws[TAGS][512];
    const int tid = threadIdx.x;
    for (int i = tid; i < TAGS*512; i += 192) Ws[0][i] = Wtag[i];
    __syncthreads();
    const int tl = tid / TAGS;            // 0..15
    const int tg = tid % TAGS;
    const int t  = blockIdx.x * 16 + tl;
    const float4* hrow = (const float4*)(Hhist + (long)t*512);
    const float4* wrow = (const float4*)(&Ws[tg][0]);
    float a0=0.f,a1=0.f,a2=0.f,a3=0.f;
    #pragma unroll 8
    for (int k = 0; k < 128; ++k) {
        const float4 h = hrow[k];
        const float4 ww = wrow[k];
        a0=fmaf(h.x,ww.x,a0); a1=fmaf(h.y,ww.y,a1);
        a2=fmaf(h.z,ww.z,a2); a3=fmaf(h.w,ww.w,a3);
    }
    feats[t*TAGS + tg] = ((a0+a1)+(a2+a3)) + btag[tg];
}

// ---------------------------------------------------------------------------
// Kernel 4: Viterbi forward scan (12 lanes of wave 0) + serial backtrack.
// bps kept in LDS (48 KB).  out[0] = score, out[1..4096] = path as floats.
// ---------------------------------------------------------------------------
__global__ __launch_bounds__(256) void viterbi_kernel(
    const float* __restrict__ feats, const float* __restrict__ trans,
    float* __restrict__ out)
{
    __shared__ float fS[256*TAGS];                 // 12 KB feats chunk
    __shared__ unsigned char bps[T_LEN*TAGS];      // 48 KB backpointers
    __shared__ float fvS[TAGS];
    const int tid = threadIdx.x;

    float tr[TAGS];
    float fv = NEGV;
    if (tid < TAGS) {
        #pragma unroll
        for (int f = 0; f < TAGS; ++f) tr[f] = trans[tid*TAGS + f];
        fv = (tid == 10) ? 0.f : NEGV;             // START = 10
    }

    for (int c = 0; c < T_LEN/256; ++c) {
        __syncthreads();
        for (int i = tid; i < 256*TAGS; i += 256) fS[i] = feats[c*256*TAGS + i];
        __syncthreads();
        if (tid < TAGS) {
            for (int s = 0; s < 256; ++s) {
                float best = -3.4e38f; int bp = 0;
                #pragma unroll
                for (int f = 0; f < TAGS; ++f) {
                    const float v = __shfl(fv, f, 64) + tr[f];
                    if (v > best) { best = v; bp = f; }   // strict > keeps first max (np semantics)
                }
                bps[(c*256+s)*TAGS + tid] = (unsigned char)bp;
                fv = best + fS[s*TAGS + tid];
            }
        }
    }
    __syncthreads();
    if (tid < TAGS) fvS[tid] = fv + trans[11*TAGS + tid];  // STOP = 11
    __syncthreads();
    if (tid == 0) {
        float bestv = fvS[0]; int best = 0;
        #pragma unroll
        for (int g = 1; g < TAGS; ++g) if (fvS[g] > bestv) { bestv = fvS[g]; best = g; }
        out[0] = bestv;
        int cur = best;
        for (int t = T_LEN-1; t >= 0; --t) {
            out[1+t] = (float)cur;
            cur = bps[t*TAGS + cur];
        }
    }
}

// ---------------------------------------------------------------------------
// Host launch.  ws layout (floats):
//   gin   [4096*2048]          = 33.5 MB
//   Hhist [4096*512]           =  8.4 MB
//   feats [4096*12]            =  0.2 MB
// ---------------------------------------------------------------------------
extern "C" void kernel_launch(void* const* d_in, const int* in_sizes, int n_in,
                              void* d_out, int out_size, void* d_ws, size_t ws_size,
                              hipStream_t stream)
{
    (void)in_sizes; (void)n_in; (void)out_size; (void)ws_size;
    const int*   sentence = (const int*)  d_in[0];
    const float* h0       = (const float*)d_in[1];
    const float* c0       = (const float*)d_in[2];
    const float* embed    = (const float*)d_in[3];
    const float* Wihf     = (const float*)d_in[4];
    const float* Whhf     = (const float*)d_in[5];
    const float* bihf     = (const float*)d_in[6];
    const float* bhhf     = (const float*)d_in[7];
    const float* Wihb     = (const float*)d_in[8];
    const float* Whhb     = (const float*)d_in[9];
    const float* bihb     = (const float*)d_in[10];
    const float* bhhb     = (const float*)d_in[11];
    const float* Wtag     = (const float*)d_in[12];
    const float* btag     = (const float*)d_in[13];
    const float* trans    = (const float*)d_in[14];
    float* out = (float*)d_out;

    float* gin   = (float*)d_ws;
    float* Hhist = gin   + (long)T_LEN*N2;
    float* feats = Hhist + (long)T_LEN*512;

    dim3 ggrid(32, 64);
    gin_gemm<<<ggrid, 256, 0, stream>>>(sentence, embed, Wihf, Wihb,
                                        bihf, bhhf, bihb, bhhb, gin);
    lstm_single<<<2, 1024, 0, stream>>>(Whhf, Whhb, h0, c0, gin, Hhist);
    feats_kernel<<<T_LEN/16, 192, 0, stream>>>(Hhist, Wtag, btag, feats);
    viterbi_kernel<<<1, 256, 0, stream>>>(feats, trans, out);
}

// Round 3
// 77792.914 us; speedup vs baseline: 1.7106x; 1.7106x over previous
//
#include <hip/hip_runtime.h>

#define T_LEN 4096
#define EMB   300
#define HD    256
#define G4    1024      // 4*HD (gate rows per direction)
#define N2    2048      // both directions
#define TAGS  12
#define NEGV  -10000.0f

// ---------------------------------------------------------------------------
// Kernel 1: g_in[t][dir*1024 + r] = embed[sent[t]] . W_ih_dir[r] + b_ih + b_hh
// Tiled f32 GEMM, M=4096 N=2048 K=300, 64x64 tiles, 256 thr, 4x4 per thread.
// ---------------------------------------------------------------------------
__global__ __launch_bounds__(256) void gin_gemm(
    const int* __restrict__ sent, const float* __restrict__ embed,
    const float* __restrict__ Wf, const float* __restrict__ Wb,
    const float* __restrict__ bihf, const float* __restrict__ bhhf,
    const float* __restrict__ bihb, const float* __restrict__ bhhb,
    float* __restrict__ gin)
{
    __shared__ float As[64][33];
    __shared__ float Bs[64][33];
    __shared__ int   sIdx[64];
    const int tid = threadIdx.x;
    const int bn = blockIdx.x;   // 0..31  (N tiles over 2048)
    const int bm = blockIdx.y;   // 0..63  (M tiles over 4096)
    if (tid < 64) sIdx[tid] = sent[bm*64 + tid];
    __syncthreads();

    float acc[4][4] = {};
    const int lr = tid >> 3;          // 0..31
    const int lk = (tid & 7) << 2;    // 0,4,..,28
    const int m0 = (tid >> 4) << 2;
    const int n0 = (tid & 15) << 2;

    for (int kc = 0; kc < 10; ++kc) {           // K chunks of 32 (covers 320, guard 300)
        const int k0 = kc*32 + lk;
        #pragma unroll
        for (int h = 0; h < 2; ++h) {
            const int row = lr + h*32;
            float4 va = make_float4(0.f,0.f,0.f,0.f);
            if (k0 + 3 < EMB)   // EMB % 4 == 0, so vectors are all-or-nothing
                va = *(const float4*)(embed + (long)sIdx[row]*EMB + k0);
            As[row][lk+0]=va.x; As[row][lk+1]=va.y; As[row][lk+2]=va.z; As[row][lk+3]=va.w;

            const int rn = bn*64 + row;          // tiles never straddle the 1024 boundary
            const float* bsrc = (rn < G4) ? (Wf + (long)rn*EMB) : (Wb + (long)(rn-G4)*EMB);
            float4 vb = make_float4(0.f,0.f,0.f,0.f);
            if (k0 + 3 < EMB)
                vb = *(const float4*)(bsrc + k0);
            Bs[row][lk+0]=vb.x; Bs[row][lk+1]=vb.y; Bs[row][lk+2]=vb.z; Bs[row][lk+3]=vb.w;
        }
        __syncthreads();
        #pragma unroll
        for (int kk = 0; kk < 32; ++kk) {
            float a[4], b[4];
            #pragma unroll
            for (int i = 0; i < 4; ++i) a[i] = As[m0+i][kk];
            #pragma unroll
            for (int i = 0; i < 4; ++i) b[i] = Bs[n0+i][kk];
            #pragma unroll
            for (int i = 0; i < 4; ++i)
                #pragma unroll
                for (int jj = 0; jj < 4; ++jj)
                    acc[i][jj] = fmaf(a[i], b[jj], acc[i][jj]);
        }
        __syncthreads();
    }

    #pragma unroll
    for (int i = 0; i < 4; ++i) {
        const int t = bm*64 + m0 + i;
        #pragma unroll
        for (int jj = 0; jj < 4; ++jj) {
            const int r = bn*64 + n0 + jj;
            const float bias = (r < G4) ? (bihf[r] + bhhf[r])
                                        : (bihb[r-G4] + bhhb[r-G4]);
            gin[(long)t*N2 + r] = acc[i][jj] + bias;
        }
    }
}

// ---------------------------------------------------------------------------
// Kernel 2: single-block-per-direction persistent BiLSTM recurrence.
// 1024 threads = 16 waves on ONE CU; thread tid owns gate row tid of W_hh,
// 256 f32 in VGPRs. Register persistence is enforced by ALIASING, not asm:
// Whh and Hhist are non-restrict, and the loop stores to Hhist, so the
// compiler cannot legally rematerialize the weight loads inside the loop.
// amdgpu_waves_per_eu(4,4) grants the full 512-VGPR/wave budget.
// ---------------------------------------------------------------------------
__global__ __launch_bounds__(1024) __attribute__((amdgpu_waves_per_eu(4, 4)))
void lstm_single(
    const float* Whh_f, const float* Whh_b,            // NOT restrict (on purpose)
    const float* __restrict__ h0, const float* __restrict__ c0,
    const float* __restrict__ gin,
    float* Hhist)                                      // NOT restrict (on purpose)
{
    const int dir  = blockIdx.x;
    const int tid  = threadIdx.x;
    const int gate = tid >> 8;        // 0:i 1:f 2:g 3:o  (wave-uniform)
    const int unit = tid & 255;

    const float* wrow = (dir ? Whh_b : Whh_f) + (long)tid * HD;
    float w[256];
    #pragma unroll
    for (int k = 0; k < 64; ++k) {
        const float4 v = ((const float4*)wrow)[k];
        w[4*k+0] = v.x; w[4*k+1] = v.y; w[4*k+2] = v.z; w[4*k+3] = v.w;
    }

    __shared__ __align__(16) float hS[HD];
    __shared__ float gv[G4];

    float cst = 0.f;
    if (tid < HD) {
        cst = c0[dir*HD + tid];
        hS[tid] = h0[dir*HD + tid];
    }

    const float* ginD = gin + dir*G4;
    float gx = ginD[(long)(dir ? T_LEN-1 : 0)*N2 + tid];

    #pragma unroll 1
    for (int s = 0; s < T_LEN; ++s) {
        const int t = dir ? (T_LEN-1-s) : s;
        float gxn = 0.f;
        if (s+1 < T_LEN) {                       // prefetch next step's gin
            const int tn = dir ? (t-1) : (t+1);
            gxn = ginD[(long)tn*N2 + tid];
        }

        __syncthreads();                         // hS stable
        const float4* h4 = (const float4*)hS;    // uniform-address broadcast reads
        float a0=0.f, a1=0.f, a2=0.f, a3=0.f;
        #pragma unroll
        for (int k = 0; k < 64; ++k) {
            const float4 hv = h4[k];
            a0 = fmaf(w[4*k+0], hv.x, a0);
            a1 = fmaf(w[4*k+1], hv.y, a1);
            a2 = fmaf(w[4*k+2], hv.z, a2);
            a3 = fmaf(w[4*k+3], hv.w, a3);
        }
        const float raw = gx + ((a0+a1)+(a2+a3));
        // each thread activates its own gate row (wave-uniform branch)
        gv[tid] = (gate == 2) ? tanhf(raw) : 1.f/(1.f + expf(-raw));
        __syncthreads();                         // gv ready; all hS reads done

        if (tid < HD) {                          // waves 0-3: pointwise update
            const float i_ = gv[unit];
            const float f_ = gv[HD   + unit];
            const float g_ = gv[2*HD + unit];
            const float o_ = gv[3*HD + unit];
            cst = fmaf(f_, cst, i_*g_);
            const float hv = o_ * tanhf(cst);
            hS[tid] = hv;                        // nobody reads hS until next barrier
            Hhist[(long)t*512 + dir*HD + tid] = hv;
        }
        gx = gxn;
    }
}

// ---------------------------------------------------------------------------
// Kernel 3: feats[t][tag] = [hf|hb][t] . W_tag[tag] + b_tag
// ---------------------------------------------------------------------------
__global__ __launch_bounds__(192) void feats_kernel(
    const float* __restrict__ Hhist, const float* __restrict__ Wtag,
    const float* __restrict__ btag, float* __restrict__ feats)
{
    __shared__ __align__(16) float Ws[TAGS][512];
    const int tid = threadIdx.x;
    for (int i = tid; i < TAGS*512; i += 192) Ws[0][i] = Wtag[i];
    __syncthreads();
    const int tl = tid / TAGS;            // 0..15
    const int tg = tid % TAGS;
    const int t  = blockIdx.x * 16 + tl;
    const float4* hrow = (const float4*)(Hhist + (long)t*512);
    const float4* wrow = (const float4*)(&Ws[tg][0]);
    float a0=0.f,a1=0.f,a2=0.f,a3=0.f;
    #pragma unroll 8
    for (int k = 0; k < 128; ++k) {
        const float4 h = hrow[k];
        const float4 ww = wrow[k];
        a0=fmaf(h.x,ww.x,a0); a1=fmaf(h.y,ww.y,a1);
        a2=fmaf(h.z,ww.z,a2); a3=fmaf(h.w,ww.w,a3);
    }
    feats[t*TAGS + tg] = ((a0+a1)+(a2+a3)) + btag[tg];
}

// ---------------------------------------------------------------------------
// Kernel 4: Viterbi forward scan (12 lanes of wave 0) + serial backtrack.
// bps kept in LDS (48 KB).  out[0] = score, out[1..4096] = path as floats.
// ---------------------------------------------------------------------------
__global__ __launch_bounds__(256) void viterbi_kernel(
    const float* __restrict__ feats, const float* __restrict__ trans,
    float* __restrict__ out)
{
    __shared__ float fS[256*TAGS];                 // 12 KB feats chunk
    __shared__ unsigned char bps[T_LEN*TAGS];      // 48 KB backpointers
    __shared__ float fvS[TAGS];
    const int tid = threadIdx.x;

    float tr[TAGS];
    float fv = NEGV;
    if (tid < TAGS) {
        #pragma unroll
        for (int f = 0; f < TAGS; ++f) tr[f] = trans[tid*TAGS + f];
        fv = (tid == 10) ? 0.f : NEGV;             // START = 10
    }

    for (int c = 0; c < T_LEN/256; ++c) {
        __syncthreads();
        for (int i = tid; i < 256*TAGS; i += 256) fS[i] = feats[c*256*TAGS + i];
        __syncthreads();
        if (tid < TAGS) {
            for (int s = 0; s < 256; ++s) {
                float best = -3.4e38f; int bp = 0;
                #pragma unroll
                for (int f = 0; f < TAGS; ++f) {
                    const float v = __shfl(fv, f, 64) + tr[f];
                    if (v > best) { best = v; bp = f; }   // strict > keeps first max (np semantics)
                }
                bps[(c*256+s)*TAGS + tid] = (unsigned char)bp;
                fv = best + fS[s*TAGS + tid];
            }
        }
    }
    __syncthreads();
    if (tid < TAGS) fvS[tid] = fv + trans[11*TAGS + tid];  // STOP = 11
    __syncthreads();
    if (tid == 0) {
        float bestv = fvS[0]; int best = 0;
        #pragma unroll
        for (int g = 1; g < TAGS; ++g) if (fvS[g] > bestv) { bestv = fvS[g]; best = g; }
        out[0] = bestv;
        int cur = best;
        for (int t = T_LEN-1; t >= 0; --t) {
            out[1+t] = (float)cur;
            cur = bps[t*TAGS + cur];
        }
    }
}

// ---------------------------------------------------------------------------
// Host launch.  ws layout (floats):
//   gin   [4096*2048]          = 33.5 MB
//   Hhist [4096*512]           =  8.4 MB
//   feats [4096*12]            =  0.2 MB
// ---------------------------------------------------------------------------
extern "C" void kernel_launch(void* const* d_in, const int* in_sizes, int n_in,
                              void* d_out, int out_size, void* d_ws, size_t ws_size,
                              hipStream_t stream)
{
    (void)in_sizes; (void)n_in; (void)out_size; (void)ws_size;
    const int*   sentence = (const int*)  d_in[0];
    const float* h0       = (const float*)d_in[1];
    const float* c0       = (const float*)d_in[2];
    const float* embed    = (const float*)d_in[3];
    const float* Wihf     = (const float*)d_in[4];
    const float* Whhf     = (const float*)d_in[5];
    const float* bihf     = (const float*)d_in[6];
    const float* bhhf     = (const float*)d_in[7];
    const float* Wihb     = (const float*)d_in[8];
    const float* Whhb     = (const float*)d_in[9];
    const float* bihb     = (const float*)d_in[10];
    const float* bhhb     = (const float*)d_in[11];
    const float* Wtag     = (const float*)d_in[12];
    const float* btag     = (const float*)d_in[13];
    const float* trans    = (const float*)d_in[14];
    float* out = (float*)d_out;

    float* gin   = (float*)d_ws;
    float* Hhist = gin   + (long)T_LEN*N2;
    float* feats = Hhist + (long)T_LEN*512;

    dim3 ggrid(32, 64);
    gin_gemm<<<ggrid, 256, 0, stream>>>(sentence, embed, Wihf, Wihb,
                                        bihf, bhhf, bihb, bhhb, gin);
    lstm_single<<<2, 1024, 0, stream>>>(Whhf, Whhb, h0, c0, gin, Hhist);
    feats_kernel<<<T_LEN/16, 192, 0, stream>>>(Hhist, Wtag, btag, feats);
    viterbi_kernel<<<1, 256, 0, stream>>>(feats, trans, out);
}

// Round 4
// 14054.103 us; speedup vs baseline: 9.4688x; 5.5352x over previous
//
#include <hip/hip_runtime.h>

#define T_LEN 4096
#define EMB   300
#define HD    256
#define G4    1024      // 4*HD (gate rows per direction)
#define N2    2048      // both directions
#define TAGS  12
#define NEGV  -10000.0f
#define SENT  0x7F7F7F7Fu   // memset byte 0x7F -> float 3.39e38; |h|<1 so never produced

// ---------------------------------------------------------------------------
// Kernel 1: g_in[t][dir*1024 + r] = embed[sent[t]] . W_ih_dir[r] + b_ih + b_hh
// ---------------------------------------------------------------------------
__global__ __launch_bounds__(256) void gin_gemm(
    const int* __restrict__ sent, const float* __restrict__ embed,
    const float* __restrict__ Wf, const float* __restrict__ Wb,
    const float* __restrict__ bihf, const float* __restrict__ bhhf,
    const float* __restrict__ bihb, const float* __restrict__ bhhb,
    float* __restrict__ gin)
{
    __shared__ float As[64][33];
    __shared__ float Bs[64][33];
    __shared__ int   sIdx[64];
    const int tid = threadIdx.x;
    const int bn = blockIdx.x;   // 0..31  (N tiles over 2048)
    const int bm = blockIdx.y;   // 0..63  (M tiles over 4096)
    if (tid < 64) sIdx[tid] = sent[bm*64 + tid];
    __syncthreads();

    float acc[4][4] = {};
    const int lr = tid >> 3;          // 0..31
    const int lk = (tid & 7) << 2;    // 0,4,..,28
    const int m0 = (tid >> 4) << 2;
    const int n0 = (tid & 15) << 2;

    for (int kc = 0; kc < 10; ++kc) {           // K chunks of 32 (covers 320, guard 300)
        const int k0 = kc*32 + lk;
        #pragma unroll
        for (int h = 0; h < 2; ++h) {
            const int row = lr + h*32;
            float4 va = make_float4(0.f,0.f,0.f,0.f);
            if (k0 + 3 < EMB)
                va = *(const float4*)(embed + (long)sIdx[row]*EMB + k0);
            As[row][lk+0]=va.x; As[row][lk+1]=va.y; As[row][lk+2]=va.z; As[row][lk+3]=va.w;

            const int rn = bn*64 + row;
            const float* bsrc = (rn < G4) ? (Wf + (long)rn*EMB) : (Wb + (long)(rn-G4)*EMB);
            float4 vb = make_float4(0.f,0.f,0.f,0.f);
            if (k0 + 3 < EMB)
                vb = *(const float4*)(bsrc + k0);
            Bs[row][lk+0]=vb.x; Bs[row][lk+1]=vb.y; Bs[row][lk+2]=vb.z; Bs[row][lk+3]=vb.w;
        }
        __syncthreads();
        #pragma unroll
        for (int kk = 0; kk < 32; ++kk) {
            float a[4], b[4];
            #pragma unroll
            for (int i = 0; i < 4; ++i) a[i] = As[m0+i][kk];
            #pragma unroll
            for (int i = 0; i < 4; ++i) b[i] = Bs[n0+i][kk];
            #pragma unroll
            for (int i = 0; i < 4; ++i)
                #pragma unroll
                for (int jj = 0; jj < 4; ++jj)
                    acc[i][jj] = fmaf(a[i], b[jj], acc[i][jj]);
        }
        __syncthreads();
    }

    #pragma unroll
    for (int i = 0; i < 4; ++i) {
        const int t = bm*64 + m0 + i;
        #pragma unroll
        for (int jj = 0; jj < 4; ++jj) {
            const int r = bn*64 + n0 + jj;
            const float bias = (r < G4) ? (bihf[r] + bhhf[r])
                                        : (bihb[r-G4] + bhhb[r-G4]);
            gin[(long)t*N2 + r] = acc[i][jj] + bias;
        }
    }
}

// ---------------------------------------------------------------------------
// Kernel 2: persistent BiLSTM, 4 blocks x 256 thr per direction.
// Block owns 64 UNITS (all 4 gates). Thread (gate,u) owns gate row
// r = gate*256 + 64*b + u with its 256 W_hh f32 pinned in VGPRs
// (asm anti-remat; 1 wave/SIMD -> 512-VGPR budget so regalloc CAN comply).
// Cross-block h exchange: sentinel-initialized Hh words, relaxed agent-scope
// atomic store/poll — data is its own flag, no release/acquire handshake.
// Grid = 29 blocks; workers at blk%4==0 so each dir's 4 workers share an XCD.
// ---------------------------------------------------------------------------
__global__ __launch_bounds__(256, 1) void lstm_persist(
    const float* Whh_f, const float* Whh_b,
    const float* __restrict__ h0, const float* __restrict__ c0,
    const float* __restrict__ gin,
    float* Hh)                         // [T][512], pre-memset to 0x7F bytes
{
    const int blk = blockIdx.x;
    if (blk & 3) return;               // dummy blocks (XCD placement spacers)
    const int w    = blk >> 2;         // 0..7
    const int dir  = w & 1;            // even->dir0 (XCD0), odd->dir1 (XCD4)
    const int b    = w >> 1;           // unit-slice 0..3
    const int tid  = threadIdx.x;
    const int gate = tid >> 6;         // wave-uniform
    const int u    = tid & 63;
    const int unit = b*64 + u;         // global unit 0..255
    const int r    = gate*HD + unit;   // gate row 0..1023

    // --- load + pin 256 weights in VGPRs ---
    const float* wrow = (dir ? Whh_b : Whh_f) + (long)r * HD;
    float wv[256];
    #pragma unroll
    for (int k = 0; k < 64; ++k) {
        const float4 v = ((const float4*)wrow)[k];
        wv[4*k+0]=v.x; wv[4*k+1]=v.y; wv[4*k+2]=v.z; wv[4*k+3]=v.w;
        asm volatile("" : "+v"(wv[4*k+0]), "+v"(wv[4*k+1]),
                          "+v"(wv[4*k+2]), "+v"(wv[4*k+3]));
    }

    __shared__ __align__(16) float hS[HD];
    __shared__ float gv[4][64];

    float cst = 0.f;
    if (gate == 0) cst = c0[dir*HD + unit];
    hS[tid] = h0[dir*HD + tid];

    const float* ginD = gin + dir*G4;
    unsigned int* HhU = (unsigned int*)Hh;
    float gx = ginD[(long)(dir ? T_LEN-1 : 0)*N2 + r];

    #pragma unroll 1
    for (int s = 0; s < T_LEN; ++s) {
        const int t = dir ? (T_LEN-1-s) : s;
        float gxn = 0.f;
        if (s+1 < T_LEN)                          // prefetch next step's gin
            gxn = ginD[(long)(dir ? t-1 : t+1)*N2 + r];

        __syncthreads();                          // hS complete
        const float4* h4 = (const float4*)hS;     // uniform-address broadcast reads
        float a0=0.f, a1=0.f, a2=0.f, a3=0.f;
        #pragma unroll
        for (int k = 0; k < 64; ++k) {
            const float4 hv = h4[k];
            a0 = fmaf(wv[4*k+0], hv.x, a0);
            a1 = fmaf(wv[4*k+1], hv.y, a1);
            a2 = fmaf(wv[4*k+2], hv.z, a2);
            a3 = fmaf(wv[4*k+3], hv.w, a3);
        }
        const float raw = gx + ((a0+a1)+(a2+a3));
        gv[gate][u] = (gate == 2) ? tanhf(raw) : 1.f/(1.f + expf(-raw));
        __syncthreads();                          // gv ready; hS reads done

        if (gate == 0) {                          // own units: local c/h update
            const float i_ = gv[0][u], f_ = gv[1][u];
            const float g_ = gv[2][u], o_ = gv[3][u];
            cst = fmaf(f_, cst, i_*g_);
            const float hv = o_ * tanhf(cst);
            hS[unit] = hv;                        // local fast path (no mem round-trip)
            __hip_atomic_store(&HhU[(long)t*512 + dir*HD + unit],
                               __float_as_uint(hv),
                               __ATOMIC_RELAXED, __HIP_MEMORY_SCOPE_AGENT);
        }
        if (s+1 < T_LEN && (tid >> 6) != b) {     // pull 192 foreign h words
            const long idx = (long)t*512 + dir*HD + tid;
            unsigned int v;
            do {
                v = __hip_atomic_load(&HhU[idx], __ATOMIC_RELAXED,
                                      __HIP_MEMORY_SCOPE_AGENT);
            } while (v == SENT);
            hS[tid] = __uint_as_float(v);
        }
        gx = gxn;
    }
}

// ---------------------------------------------------------------------------
// Kernel 3: feats[t][tag] = [hf|hb][t] . W_tag[tag] + b_tag
// ---------------------------------------------------------------------------
__global__ __launch_bounds__(192) void feats_kernel(
    const float* __restrict__ Hhist, const float* __restrict__ Wtag,
    const float* __restrict__ btag, float* __restrict__ feats)
{
    __shared__ __align__(16) float Ws[TAGS][512];
    const int tid = threadIdx.x;
    for (int i = tid; i < TAGS*512; i += 192) Ws[0][i] = Wtag[i];
    __syncthreads();
    const int tl = tid / TAGS;            // 0..15
    const int tg = tid % TAGS;
    const int t  = blockIdx.x * 16 + tl;
    const float4* hrow = (const float4*)(Hhist + (long)t*512);
    const float4* wrow = (const float4*)(&Ws[tg][0]);
    float a0=0.f,a1=0.f,a2=0.f,a3=0.f;
    #pragma unroll 8
    for (int k = 0; k < 128; ++k) {
        const float4 h = hrow[k];
        const float4 ww = wrow[k];
        a0=fmaf(h.x,ww.x,a0); a1=fmaf(h.y,ww.y,a1);
        a2=fmaf(h.z,ww.z,a2); a3=fmaf(h.w,ww.w,a3);
    }
    feats[t*TAGS + tg] = ((a0+a1)+(a2+a3)) + btag[tg];
}

// ---------------------------------------------------------------------------
// Kernel 4: Viterbi forward scan (12 lanes) + serial backtrack.
// ---------------------------------------------------------------------------
__global__ __launch_bounds__(256) void viterbi_kernel(
    const float* __restrict__ feats, const float* __restrict__ trans,
    float* __restrict__ out)
{
    __shared__ float fS[256*TAGS];                 // 12 KB feats chunk
    __shared__ unsigned char bps[T_LEN*TAGS];      // 48 KB backpointers
    __shared__ float fvS[TAGS];
    const int tid = threadIdx.x;

    float tr[TAGS];
    float fv = NEGV;
    if (tid < TAGS) {
        #pragma unroll
        for (int f = 0; f < TAGS; ++f) tr[f] = trans[tid*TAGS + f];
        fv = (tid == 10) ? 0.f : NEGV;             // START = 10
    }

    for (int c = 0; c < T_LEN/256; ++c) {
        __syncthreads();
        for (int i = tid; i < 256*TAGS; i += 256) fS[i] = feats[c*256*TAGS + i];
        __syncthreads();
        if (tid < TAGS) {
            for (int s = 0; s < 256; ++s) {
                float best = -3.4e38f; int bp = 0;
                #pragma unroll
                for (int f = 0; f < TAGS; ++f) {
                    const float v = __shfl(fv, f, 64) + tr[f];
                    if (v > best) { best = v; bp = f; }   // strict > = np argmax semantics
                }
                bps[(c*256+s)*TAGS + tid] = (unsigned char)bp;
                fv = best + fS[s*TAGS + tid];
            }
        }
    }
    __syncthreads();
    if (tid < TAGS) fvS[tid] = fv + trans[11*TAGS + tid];  // STOP = 11
    __syncthreads();
    if (tid == 0) {
        float bestv = fvS[0]; int best = 0;
        #pragma unroll
        for (int g = 1; g < TAGS; ++g) if (fvS[g] > bestv) { bestv = fvS[g]; best = g; }
        out[0] = bestv;
        int cur = best;
        for (int t = T_LEN-1; t >= 0; --t) {
            out[1+t] = (float)cur;
            cur = bps[t*TAGS + cur];
        }
    }
}

// ---------------------------------------------------------------------------
// Host launch.  ws layout (floats):
//   gin   [4096*2048] = 33.5 MB
//   Hh    [4096*512]  =  8.4 MB  (sentinel-initialized each launch)
//   feats [4096*12]   =  0.2 MB
// ---------------------------------------------------------------------------
extern "C" void kernel_launch(void* const* d_in, const int* in_sizes, int n_in,
                              void* d_out, int out_size, void* d_ws, size_t ws_size,
                              hipStream_t stream)
{
    (void)in_sizes; (void)n_in; (void)out_size; (void)ws_size;
    const int*   sentence = (const int*)  d_in[0];
    const float* h0       = (const float*)d_in[1];
    const float* c0       = (const float*)d_in[2];
    const float* embed    = (const float*)d_in[3];
    const float* Wihf     = (const float*)d_in[4];
    const float* Whhf     = (const float*)d_in[5];
    const float* bihf     = (const float*)d_in[6];
    const float* bhhf     = (const float*)d_in[7];
    const float* Wihb     = (const float*)d_in[8];
    const float* Whhb     = (const float*)d_in[9];
    const float* bihb     = (const float*)d_in[10];
    const float* bhhb     = (const float*)d_in[11];
    const float* Wtag     = (const float*)d_in[12];
    const float* btag     = (const float*)d_in[13];
    const float* trans    = (const float*)d_in[14];
    float* out = (float*)d_out;

    float* gin   = (float*)d_ws;
    float* Hh    = gin + (long)T_LEN*N2;
    float* feats = Hh  + (long)T_LEN*512;

    // sentinel-fill Hh: data-is-the-flag protocol
    hipMemsetAsync(Hh, 0x7F, (size_t)T_LEN*512*sizeof(float), stream);

    dim3 ggrid(32, 64);
    gin_gemm<<<ggrid, 256, 0, stream>>>(sentence, embed, Wihf, Wihb,
                                        bihf, bhhf, bihb, bhhb, gin);
    lstm_persist<<<29, 256, 0, stream>>>(Whhf, Whhb, h0, c0, gin, Hh);
    feats_kernel<<<T_LEN/16, 192, 0, stream>>>(Hh, Wtag, btag, feats);
    viterbi_kernel<<<1, 256, 0, stream>>>(feats, trans, out);
}

// Round 5
// 8140.060 us; speedup vs baseline: 16.3483x; 1.7265x over previous
//
#include <hip/hip_runtime.h>

#define T_LEN 4096
#define EMB   300
#define HD    256
#define G4    1024      // 4*HD (gate rows per direction)
#define N2    2048      // both directions
#define TAGS  12
#define NEGV  -10000.0f
#define SENT  0x7F7F7F7Fu   // memset byte 0x7F -> float 3.39e38; |h|<1 so never produced

// ---------------------------------------------------------------------------
// Kernel 1: g_in[t][dir*1024 + r] = embed[sent[t]] . W_ih_dir[r] + b_ih + b_hh
// ---------------------------------------------------------------------------
__global__ __launch_bounds__(256) void gin_gemm(
    const int* __restrict__ sent, const float* __restrict__ embed,
    const float* __restrict__ Wf, const float* __restrict__ Wb,
    const float* __restrict__ bihf, const float* __restrict__ bhhf,
    const float* __restrict__ bihb, const float* __restrict__ bhhb,
    float* __restrict__ gin)
{
    __shared__ float As[64][33];
    __shared__ float Bs[64][33];
    __shared__ int   sIdx[64];
    const int tid = threadIdx.x;
    const int bn = blockIdx.x;   // 0..31  (N tiles over 2048)
    const int bm = blockIdx.y;   // 0..63  (M tiles over 4096)
    if (tid < 64) sIdx[tid] = sent[bm*64 + tid];
    __syncthreads();

    float acc[4][4] = {};
    const int lr = tid >> 3;          // 0..31
    const int lk = (tid & 7) << 2;    // 0,4,..,28
    const int m0 = (tid >> 4) << 2;
    const int n0 = (tid & 15) << 2;

    for (int kc = 0; kc < 10; ++kc) {           // K chunks of 32 (covers 320, guard 300)
        const int k0 = kc*32 + lk;
        #pragma unroll
        for (int h = 0; h < 2; ++h) {
            const int row = lr + h*32;
            float4 va = make_float4(0.f,0.f,0.f,0.f);
            if (k0 + 3 < EMB)
                va = *(const float4*)(embed + (long)sIdx[row]*EMB + k0);
            As[row][lk+0]=va.x; As[row][lk+1]=va.y; As[row][lk+2]=va.z; As[row][lk+3]=va.w;

            const int rn = bn*64 + row;
            const float* bsrc = (rn < G4) ? (Wf + (long)rn*EMB) : (Wb + (long)(rn-G4)*EMB);
            float4 vb = make_float4(0.f,0.f,0.f,0.f);
            if (k0 + 3 < EMB)
                vb = *(const float4*)(bsrc + k0);
            Bs[row][lk+0]=vb.x; Bs[row][lk+1]=vb.y; Bs[row][lk+2]=vb.z; Bs[row][lk+3]=vb.w;
        }
        __syncthreads();
        #pragma unroll
        for (int kk = 0; kk < 32; ++kk) {
            float a[4], b[4];
            #pragma unroll
            for (int i = 0; i < 4; ++i) a[i] = As[m0+i][kk];
            #pragma unroll
            for (int i = 0; i < 4; ++i) b[i] = Bs[n0+i][kk];
            #pragma unroll
            for (int i = 0; i < 4; ++i)
                #pragma unroll
                for (int jj = 0; jj < 4; ++jj)
                    acc[i][jj] = fmaf(a[i], b[jj], acc[i][jj]);
        }
        __syncthreads();
    }

    #pragma unroll
    for (int i = 0; i < 4; ++i) {
        const int t = bm*64 + m0 + i;
        #pragma unroll
        for (int jj = 0; jj < 4; ++jj) {
            const int r = bn*64 + n0 + jj;
            const float bias = (r < G4) ? (bihf[r] + bhhf[r])
                                        : (bihb[r-G4] + bhhb[r-G4]);
            gin[(long)t*N2 + r] = acc[i][jj] + bias;
        }
    }
}

// ---------------------------------------------------------------------------
// Kernel 2: persistent BiLSTM, 8 blocks x 256 thr per direction.
// Block owns 32 UNITS. Thread (gate, half, u) owns HALF of gate row
// grow = gate*256 + b*32 + u  (128 weights -> ~175 VGPRs total, UNDER the
// allocator's empirical ~190 comfort cap; waves_per_eu(1,1) pins the
// occupancy target so there is no spill-for-occupancy incentive).
// Wave map: w0 = gates{0,1} half0, w1 = gates{0,1} half1,
//           w2 = gates{2,3} half0, w3 = gates{2,3} half1.
// Halves reduced via LDS. Cross-block h: sentinel words, relaxed
// agent-scope store/poll (data is the flag). dir0 workers at blk%8==0
// (one XCD), dir1 at blk%8==4.
// ---------------------------------------------------------------------------
__global__ __launch_bounds__(256) __attribute__((amdgpu_waves_per_eu(1, 1)))
void lstm_persist(
    const float* Whh_f, const float* Whh_b,            // NOT restrict (anti-remat)
    const float* __restrict__ h0, const float* __restrict__ c0,
    const float* __restrict__ gin,
    float* Hh)                                          // [T][512], 0x7F-filled
{
    const int blk = blockIdx.x;
    const int m8  = blk & 7;
    if (m8 != 0 && m8 != 4) return;     // XCD placement spacers
    const int dir = (m8 == 4);
    const int b   = blk >> 3;           // unit-slice 0..7
    const int tid = threadIdx.x;
    const int u    = tid & 31;
    const int gate = ((tid >> 6) & 2) | ((tid >> 5) & 1);
    const int half = (tid >> 6) & 1;
    const int unit = b*32 + u;                 // global unit 0..255
    const int grow = gate*HD + unit;           // gate row 0..1023
    const int row  = gate*32 + u;              // row-local 0..127

    // --- load + pin 128 weights (half a gate row) in VGPRs ---
    const float* wrow = (dir ? Whh_b : Whh_f) + (long)grow*HD + half*128;
    float wv[128];
    #pragma unroll
    for (int k = 0; k < 32; ++k) {
        const float4 v = ((const float4*)wrow)[k];
        wv[4*k+0]=v.x; wv[4*k+1]=v.y; wv[4*k+2]=v.z; wv[4*k+3]=v.w;
        asm volatile("" : "+v"(wv[4*k+0]), "+v"(wv[4*k+1]),
                          "+v"(wv[4*k+2]), "+v"(wv[4*k+3]));
    }

    __shared__ __align__(16) float hS[HD];
    __shared__ float ps[128];       // half-1 partial sums
    __shared__ float gvS[128];      // activated gates for own 32 units

    float cst = 0.f;
    if (tid < 32) cst = c0[dir*HD + unit];     // owners: tid 0..31 (u==tid)
    hS[tid] = h0[dir*HD + tid];

    const float* ginD = gin + dir*G4;
    unsigned int* HhU = (unsigned int*)Hh;
    float gx = (half == 0) ? ginD[(long)(dir ? T_LEN-1 : 0)*N2 + grow] : 0.f;

    #pragma unroll 1
    for (int s = 0; s < T_LEN; ++s) {
        const int t = dir ? (T_LEN-1-s) : s;
        float gxn = 0.f;
        if (half == 0 && s+1 < T_LEN)          // prefetch next step's gin (waves 0,2)
            gxn = ginD[(long)(dir ? t-1 : t+1)*N2 + grow];

        __syncthreads();                       // (A) hS complete for step s
        const float4* h4 = (const float4*)(hS + half*128);   // uniform-addr broadcast
        float a0=0.f, a1=0.f, a2=0.f, a3=0.f;
        #pragma unroll
        for (int k = 0; k < 32; ++k) {
            const float4 hv = h4[k];
            a0 = fmaf(wv[4*k+0], hv.x, a0);
            a1 = fmaf(wv[4*k+1], hv.y, a1);
            a2 = fmaf(wv[4*k+2], hv.z, a2);
            a3 = fmaf(wv[4*k+3], hv.w, a3);
        }
        const float a = (a0+a1)+(a2+a3);
        if (half == 1) ps[row] = a;
        __syncthreads();                       // (B) partials ready

        if (half == 0) {                       // waves 0,2 finalize + activate
            const float raw = a + ps[row] + gx;
            gvS[row] = (gate == 2) ? tanhf(raw) : 1.f/(1.f + expf(-raw));
        }
        __syncthreads();                       // (C) gvS ready

        if (tid < 32) {                        // owners: c/h update for own units
            const float i_ = gvS[u],    f_ = gvS[32+u];
            const float g_ = gvS[64+u], o_ = gvS[96+u];
            cst = fmaf(f_, cst, i_*g_);
            const float hv = o_ * tanhf(cst);
            hS[unit] = hv;
            __hip_atomic_store(&HhU[(long)t*512 + dir*HD + unit],
                               __float_as_uint(hv),
                               __ATOMIC_RELAXED, __HIP_MEMORY_SCOPE_AGENT);
        }
        if (s+1 < T_LEN && (tid >> 5) != b) {  // pull 224 foreign h words
            const long idx = (long)t*512 + dir*HD + tid;
            unsigned int v;
            do {
                v = __hip_atomic_load(&HhU[idx], __ATOMIC_RELAXED,
                                      __HIP_MEMORY_SCOPE_AGENT);
            } while (v == SENT);
            hS[tid] = __uint_as_float(v);
        }
        gx = gxn;
    }
}

// ---------------------------------------------------------------------------
// Kernel 3: feats[t][tag] = [hf|hb][t] . W_tag[tag] + b_tag
// ---------------------------------------------------------------------------
__global__ __launch_bounds__(192) void feats_kernel(
    const float* __restrict__ Hhist, const float* __restrict__ Wtag,
    const float* __restrict__ btag, float* __restrict__ feats)
{
    __shared__ __align__(16) float Ws[TAGS][512];
    const int tid = threadIdx.x;
    for (int i = tid; i < TAGS*512; i += 192) Ws[0][i] = Wtag[i];
    __syncthreads();
    const int tl = tid / TAGS;            // 0..15
    const int tg = tid % TAGS;
    const int t  = blockIdx.x * 16 + tl;
    const float4* hrow = (const float4*)(Hhist + (long)t*512);
    const float4* wrow = (const float4*)(&Ws[tg][0]);
    float a0=0.f,a1=0.f,a2=0.f,a3=0.f;
    #pragma unroll 8
    for (int k = 0; k < 128; ++k) {
        const float4 h = hrow[k];
        const float4 ww = wrow[k];
        a0=fmaf(h.x,ww.x,a0); a1=fmaf(h.y,ww.y,a1);
        a2=fmaf(h.z,ww.z,a2); a3=fmaf(h.w,ww.w,a3);
    }
    feats[t*TAGS + tg] = ((a0+a1)+(a2+a3)) + btag[tg];
}

// ---------------------------------------------------------------------------
// Kernel 4: Viterbi forward scan (12 lanes) + serial backtrack.
// ---------------------------------------------------------------------------
__global__ __launch_bounds__(256) void viterbi_kernel(
    const float* __restrict__ feats, const float* __restrict__ trans,
    float* __restrict__ out)
{
    __shared__ float fS[256*TAGS];                 // 12 KB feats chunk
    __shared__ unsigned char bps[T_LEN*TAGS];      // 48 KB backpointers
    __shared__ float fvS[TAGS];
    const int tid = threadIdx.x;

    float tr[TAGS];
    float fv = NEGV;
    if (tid < TAGS) {
        #pragma unroll
        for (int f = 0; f < TAGS; ++f) tr[f] = trans[tid*TAGS + f];
        fv = (tid == 10) ? 0.f : NEGV;             // START = 10
    }

    for (int c = 0; c < T_LEN/256; ++c) {
        __syncthreads();
        for (int i = tid; i < 256*TAGS; i += 256) fS[i] = feats[c*256*TAGS + i];
        __syncthreads();
        if (tid < TAGS) {
            for (int s = 0; s < 256; ++s) {
                float best = -3.4e38f; int bp = 0;
                #pragma unroll
                for (int f = 0; f < TAGS; ++f) {
                    const float v = __shfl(fv, f, 64) + tr[f];
                    if (v > best) { best = v; bp = f; }   // strict > = np argmax semantics
                }
                bps[(c*256+s)*TAGS + tid] = (unsigned char)bp;
                fv = best + fS[s*TAGS + tid];
            }
        }
    }
    __syncthreads();
    if (tid < TAGS) fvS[tid] = fv + trans[11*TAGS + tid];  // STOP = 11
    __syncthreads();
    if (tid == 0) {
        float bestv = fvS[0]; int best = 0;
        #pragma unroll
        for (int g = 1; g < TAGS; ++g) if (fvS[g] > bestv) { bestv = fvS[g]; best = g; }
        out[0] = bestv;
        int cur = best;
        for (int t = T_LEN-1; t >= 0; --t) {
            out[1+t] = (float)cur;
            cur = bps[t*TAGS + cur];
        }
    }
}

// ---------------------------------------------------------------------------
// Host launch.  ws layout (floats):
//   gin   [4096*2048] = 33.5 MB
//   Hh    [4096*512]  =  8.4 MB  (sentinel-initialized each launch)
//   feats [4096*12]   =  0.2 MB
// ---------------------------------------------------------------------------
extern "C" void kernel_launch(void* const* d_in, const int* in_sizes, int n_in,
                              void* d_out, int out_size, void* d_ws, size_t ws_size,
                              hipStream_t stream)
{
    (void)in_sizes; (void)n_in; (void)out_size; (void)ws_size;
    const int*   sentence = (const int*)  d_in[0];
    const float* h0       = (const float*)d_in[1];
    const float* c0       = (const float*)d_in[2];
    const float* embed    = (const float*)d_in[3];
    const float* Wihf     = (const float*)d_in[4];
    const float* Whhf     = (const float*)d_in[5];
    const float* bihf     = (const float*)d_in[6];
    const float* bhhf     = (const float*)d_in[7];
    const float* Wihb     = (const float*)d_in[8];
    const float* Whhb     = (const float*)d_in[9];
    const float* bihb     = (const float*)d_in[10];
    const float* bhhb     = (const float*)d_in[11];
    const float* Wtag     = (const float*)d_in[12];
    const float* btag     = (const float*)d_in[13];
    const float* trans    = (const float*)d_in[14];
    float* out = (float*)d_out;

    float* gin   = (float*)d_ws;
    float* Hh    = gin + (long)T_LEN*N2;
    float* feats = Hh  + (long)T_LEN*512;

    // sentinel-fill Hh: data-is-the-flag protocol
    hipMemsetAsync(Hh, 0x7F, (size_t)T_LEN*512*sizeof(float), stream);

    dim3 ggrid(32, 64);
    gin_gemm<<<ggrid, 256, 0, stream>>>(sentence, embed, Wihf, Wihb,
                                        bihf, bhhf, bihb, bhhb, gin);
    lstm_persist<<<61, 256, 0, stream>>>(Whhf, Whhb, h0, c0, gin, Hh);
    feats_kernel<<<T_LEN/16, 192, 0, stream>>>(Hh, Wtag, btag, feats);
    viterbi_kernel<<<1, 256, 0, stream>>>(feats, trans, out);
}